// Round 13
// baseline (316.214 us; speedup 1.0000x reference)
//
#include <hip/hip_runtime.h>
#include <hip/hip_bf16.h>
#include <math.h>

#define HH  256      // d_model
#define NHD 32       // state halves
#define LL  8192     // sequence length
#define BB  16       // batch
#define HN  (HH*NHD) // 8192
#define BH  (BB*HH)  // 4096
#define LC  256      // chunk length
#define NG  (LL/LC)  // 32 chunks per row
#define NINST (BB*NG) // 512 chunk instances per h

typedef __attribute__((ext_vector_type(8))) short short8;
typedef __attribute__((ext_vector_type(4))) float floatx4;

__device__ __forceinline__ unsigned short f2bf(float f) {
  unsigned u = __float_as_uint(f);
  unsigned r = (u + 0x7FFF + ((u >> 16) & 1)) >> 16;
  return (unsigned short)r;
}
__device__ __forceinline__ unsigned packbf2(float a, float b) {
  return (unsigned)f2bf(a) | ((unsigned)f2bf(b) << 16);
}
__device__ __forceinline__ float gelu_t(float y) {
  float y2 = y * y;
  float arg = 1.5957691216f * fmaf(0.044715f * y2, y, y);
  return y / (1.f + __expf(-arg));
}

// ---------------------------------------------------------------------------
// Param precompute. P[k*HN + h*NHD + n]:
// 0=wr 1=wi 2=c0r 3=c0i 4=c1r 5=c1i 6=wLr 7=wLi 8=ar(dtA re) 9=ai(dtA im)
// ---------------------------------------------------------------------------
__global__ void precomp_kernel(const float* __restrict__ log_dt,
                               const float* __restrict__ A_real,
                               const float* __restrict__ A_imag,
                               const float* __restrict__ C_real,
                               const float* __restrict__ C_imag,
                               float* __restrict__ P) {
  int i = blockIdx.x * blockDim.x + threadIdx.x;
  if (i >= HN) return;
  int h = i >> 5;
  double dt  = exp((double)log_dt[h]);
  double Are = -exp((double)A_real[i]);
  double Aim = (double)A_imag[i];
  double ar = Are * dt, ai = Aim * dt;
  double ea = exp(ar);
  double wr = ea * cos(ai), wi = ea * sin(ai);
  double em_r = wr - 1.0, em_i = wi;
  double den = Are * Are + Aim * Aim;
  double rr = (em_r * Are + em_i * Aim) / den;
  double ri = (em_i * Are - em_r * Aim) / den;
  P[0*HN + i] = (float)wr;
  P[1*HN + i] = (float)wi;
  {
    double cr = (double)C_real[i], ci = (double)C_imag[i];
    P[2*HN + i] = (float)(2.0 * (cr * rr - ci * ri));
    P[3*HN + i] = (float)(2.0 * (cr * ri + ci * rr));
  }
  {
    double cr = (double)C_real[HN + i], ci = (double)C_imag[HN + i];
    P[4*HN + i] = (float)(2.0 * (cr * rr - ci * ri));
    P[5*HN + i] = (float)(2.0 * (cr * ri + ci * rr));
  }
  {
    double arL = ar * (double)LC, aiL = ai * (double)LC;
    double eaL = exp(arL);
    P[6*HN + i] = (float)(eaL * cos(aiL));
    P[7*HN + i] = (float)(eaL * sin(aiL));
  }
  P[8*HN + i] = (float)ar;
  P[9*HN + i] = (float)ai;
}

// ---------------------------------------------------------------------------
// W (512,256) f32 -> Wf fragment-order bf16:
// chunk ((og*8+ks)*16+ln)*4+lg holds W[og*16+ln][ks*32+lg*8+e], e in [0,8).
// ---------------------------------------------------------------------------
__global__ __launch_bounds__(256) void wt_frag_kernel(const float* __restrict__ W,
                                                      unsigned short* __restrict__ Wf) {
  int og = blockIdx.x;                       // 0..31
  #pragma unroll
  for (int i = 0; i < 2; ++i) {
    int j = i * 256 + threadIdx.x;           // 0..511 = ks*64 + ln*4 + lg
    int ks = j >> 6, ln = (j >> 2) & 15, lg = j & 3;
    const float* src = W + (size_t)(og * 16 + ln) * 256 + ks * 32 + lg * 8;
    short8 vv;
    #pragma unroll
    for (int e = 0; e < 8; ++e) vv[e] = (short)f2bf(src[e]);
    ((short8*)Wf)[og * 512 + j] = vv;
  }
}

// ---------------------------------------------------------------------------
// kf/kb tables: kf[h][d] = sum_n Re(c0_n w_n^d), kb same with c1.
// ---------------------------------------------------------------------------
__global__ __launch_bounds__(256) void kprep_kernel(const float* __restrict__ P,
                                                    float* __restrict__ Kf,
                                                    float* __restrict__ Kb) {
  int i = blockIdx.x * 256 + threadIdx.x;   // h*256 + d
  int d = i & 255, h = i >> 8;
  float fd = (float)d;
  float sf = 0.f, sb = 0.f;
  #pragma unroll 4
  for (int n = 0; n < NHD; ++n) {
    int j = h * NHD + n;
    float m  = __expf(fd * P[8*HN + j]);
    float ph = fd * P[9*HN + j];
    float cs = cosf(ph), sn = sinf(ph);
    float re = m * cs, im = m * sn;
    sf += P[2*HN + j] * re - P[3*HN + j] * im;
    sb += P[4*HN + j] * re - P[5*HN + j] * im;
  }
  Kf[i] = sf;
  Kb[i] = sb;
}

// ---------------------------------------------------------------------------
// T' fragment-order: chunk idx (((h*16+tt)*8+ks)*16+ln)*4+lg holds
// T[t=tt*16+ln][s=ks*32+lg*8+e], e in [0,8).
// ---------------------------------------------------------------------------
__global__ __launch_bounds__(256) void tprep_kernel(const float* __restrict__ Kf,
                                                    const float* __restrict__ Kb,
                                                    const float* __restrict__ Dv,
                                                    unsigned short* __restrict__ T) {
  int h = blockIdx.x, tt = blockIdx.y;
  const float* kf = Kf + h * 256;
  const float* kb = Kb + h * 256;
  float dh = Dv[h];
  short8* out = (short8*)T;
  #pragma unroll
  for (int i = 0; i < 2; ++i) {
    int j = i * 256 + threadIdx.x;          // 0..511 = ks*64 + ln*4 + lg
    int ks = j >> 6, ln = (j >> 2) & 15, lg = j & 3;
    int t = tt * 16 + ln;
    short8 vv;
    #pragma unroll
    for (int e = 0; e < 8; ++e) {
      int s = ks * 32 + lg * 8 + e;
      int d = t - s;
      float v = (d > 0) ? kf[d] : ((d < 0) ? kb[-d - 1] : (kf[0] + dh));
      vv[e] = (short)f2bf(v);
    }
    out[(size_t)(h * 16 + tt) * 512 + j] = vv;
  }
}

// ---------------------------------------------------------------------------
// E' fragment-order: chunk (((h*16+tt)*4+ks)*16+ln)*4+lg holds E[t][k],
// t=tt*16+ln, k=ks*32+lg*8+e. k<64: pairs (Re, -Im) of c0*w^{t+1};
// k>=64: pairs of c1*w^{LC-1-t}. Direct exp.
// ---------------------------------------------------------------------------
__global__ __launch_bounds__(256) void eprep_kernel(const float* __restrict__ P,
                                                    unsigned short* __restrict__ E) {
  int h = blockIdx.x, tt = blockIdx.y;
  int j = threadIdx.x;                       // 0..255 = ks*64 + ln*4 + lg
  int ks = j >> 6, ln = (j >> 2) & 15, lg = j & 3;
  int t = tt * 16 + ln;
  int k0 = ks * 32 + lg * 8;
  short8 vv;
  if (k0 < 64) {
    float d = (float)(t + 1);
    #pragma unroll
    for (int q = 0; q < 4; ++q) {
      int n = (k0 >> 1) + q;
      int idx = h * NHD + n;
      float m  = __expf(d * P[8*HN + idx]);
      float ph = d * P[9*HN + idx];
      float re = m * cosf(ph), im = m * sinf(ph);
      float cr = P[2*HN + idx], ci = P[3*HN + idx];
      float zr = cr * re - ci * im;
      float zi = cr * im + ci * re;
      vv[2*q]   = (short)f2bf(zr);
      vv[2*q+1] = (short)f2bf(-zi);
    }
  } else {
    float d = (float)(LC - 1 - t);
    #pragma unroll
    for (int q = 0; q < 4; ++q) {
      int n = ((k0 - 64) >> 1) + q;
      int idx = h * NHD + n;
      float m  = __expf(d * P[8*HN + idx]);
      float ph = d * P[9*HN + idx];
      float re = m * cosf(ph), im = m * sinf(ph);
      float cr = P[4*HN + idx], ci = P[5*HN + idx];
      float zr = cr * re - ci * im;
      float zi = cr * im + ci * re;
      vv[2*q]   = (short)f2bf(zr);
      vv[2*q+1] = (short)f2bf(-zi);
    }
  }
  ((short8*)E)[(size_t)(h * 16 + tt) * 256 + j] = vv;
}

// ---------------------------------------------------------------------------
// V' fragment-order: chunk (((h*8+mt)*8+ks)*16+ln)*4+lg, row=mt*16+ln:
// row<64: comp(row&1) of w^{LC-1-s}; row>=64: comp of w^s; s=ks*32+lg*8+e.
// ---------------------------------------------------------------------------
__global__ __launch_bounds__(256) void vprep_kernel(const float* __restrict__ P,
                                                    unsigned short* __restrict__ V) {
  int h = blockIdx.x, mt = blockIdx.y;       // mt in [0,8)
  #pragma unroll
  for (int i = 0; i < 2; ++i) {
    int j = i * 256 + threadIdx.x;           // 0..511
    int ks = j >> 6, ln = (j >> 2) & 15, lg = j & 3;
    int row = mt * 16 + ln;
    int dir = row >> 6, nc = row & 63;
    int n = nc >> 1, comp = nc & 1;
    int idx = h * NHD + n;
    float arn = P[8*HN + idx], ain = P[9*HN + idx];
    short8 vv;
    #pragma unroll
    for (int e = 0; e < 8; ++e) {
      int s = ks * 32 + lg * 8 + e;
      float d = (float)(dir ? s : (LC - 1 - s));
      float m = __expf(d * arn);
      float ph = d * ain;
      float v = m * (comp ? sinf(ph) : cosf(ph));
      vv[e] = (short)f2bf(v);
    }
    ((short8*)V)[(size_t)(h * 8 + mt) * 512 + j] = vv;
  }
}

// ---------------------------------------------------------------------------
// x (L,B,H) f32 -> UF fragment-order bf16: chunk (((h*32+it)*8+ks)*16+ln)*4+lg
// = u[b][h][l = g*256 + ks*32 + lg*8 + e], inst = b*32+g = it*16+ln.
// ---------------------------------------------------------------------------
__global__ __launch_bounds__(256) void transpose_kernel(const float* __restrict__ x,
                                                        unsigned short* __restrict__ UF) {
  __shared__ unsigned short tile[32][264];
  int b  = blockIdx.x;
  int lb = blockIdx.y * 32;
  int tid = threadIdx.x;
  int g = lb >> 8, ks = (lb & 255) >> 5;
  int inst = b * 32 + g, it = inst >> 4, lnw = inst & 15;
  #pragma unroll
  for (int i = 0; i < 8; ++i) {
    int idx = i * 256 + tid;                 // 0..2047
    int row = idx >> 6, c4 = idx & 63;
    float4 v = *(const float4*)(x + (size_t)(lb + row) * BH + b * 256 + c4 * 4);
    ushort4 u4v;
    u4v.x = f2bf(v.x); u4v.y = f2bf(v.y); u4v.z = f2bf(v.z); u4v.w = f2bf(v.w);
    *(ushort4*)&tile[row][c4 * 4] = u4v;
  }
  __syncthreads();
  short8* out = (short8*)UF;
  #pragma unroll
  for (int i = 0; i < 4; ++i) {
    int j = i * 256 + tid;                   // 0..1023
    int h = j >> 2, lg = j & 3;
    short8 vv;
    #pragma unroll
    for (int e = 0; e < 8; ++e) vv[e] = (short)tile[lg * 8 + e][h];
    out[(size_t)(h * 32 + it) * 512 + ks * 64 + lnw * 4 + lg] = vv;
  }
}

// ---------------------------------------------------------------------------
// B-fragment loaders (shared by sfin / yloc): contiguous 1KB wave-loads.
// ---------------------------------------------------------------------------
__device__ __forceinline__ void load_bu(const short8* __restrict__ U8, int h, int it,
                                        int ln, int lg, short8 (&Bf)[8]) {
  size_t ub = (size_t)(h * 32 + it) * 512 + ln * 4 + lg;
  #pragma unroll
  for (int ks = 0; ks < 8; ++ks) Bf[ks] = U8[ub + ks * 64];
}
__device__ __forceinline__ void load_bs(const short8* __restrict__ S8, int h, int it,
                                        int ln, int lg, short8 (&Sf)[4]) {
  size_t sb = (size_t)(h * 32 + it) * 256 + ln * 4 + lg;
  #pragma unroll
  for (int ks = 0; ks < 4; ++ks) Sf[ks] = S8[sb + ks * 64];
}

// ---------------------------------------------------------------------------
// Chunk-final states: Sfin[h][inst][k] f32 = V'_h . u.
// Grid 512 = (ihalf, h): 2 blocks/CU -> 4 waves/SIMD. Each block does 16
// itiles; V'_h read per block (2nd read L2-hit: same XCD since bid%8=h%8).
// ---------------------------------------------------------------------------
__global__ __launch_bounds__(512, 2) void sfin_mfma(const unsigned short* __restrict__ V,
                                                    const unsigned short* __restrict__ UF,
                                                    float* __restrict__ Sfin) {
  int tid = threadIdx.x, w = tid >> 6, lane = tid & 63;
  int ln = lane & 15, lg = lane >> 4;
  int bid = blockIdx.x;
  int h = bid & 255, itb = (bid >> 8) * 16;
  const short8* U8 = (const short8*)UF;
  const short8* V8 = (const short8*)V;

  short8 Vf[8];
  size_t vb = (size_t)(h * 8 + w) * 512 + ln * 4 + lg;
  #pragma unroll
  for (int ks = 0; ks < 8; ++ks) Vf[ks] = V8[vb + ks * 64];

  short8 BfA[8], BfB[8];
  load_bu(U8, h, itb, ln, lg, BfA);

  for (int it = itb; it < itb + 16; it += 2) {
    load_bu(U8, h, it + 1, ln, lg, BfB);
    {
      floatx4 acc = (floatx4){0.f, 0.f, 0.f, 0.f};
      #pragma unroll
      for (int ks = 0; ks < 8; ++ks)
        acc = __builtin_amdgcn_mfma_f32_16x16x32_bf16(Vf[ks], BfA[ks], acc, 0, 0, 0);
      float* sp = Sfin + ((size_t)h * NINST + it * 16 + ln) * 128 + w * 16 + lg * 4;
      *(float4*)sp = (float4){acc[0], acc[1], acc[2], acc[3]};
    }
    if (it + 2 < itb + 16) load_bu(U8, h, it + 2, ln, lg, BfA);
    {
      floatx4 acc = (floatx4){0.f, 0.f, 0.f, 0.f};
      #pragma unroll
      for (int ks = 0; ks < 8; ++ks)
        acc = __builtin_amdgcn_mfma_f32_16x16x32_bf16(Vf[ks], BfB[ks], acc, 0, 0, 0);
      float* sp = Sfin + ((size_t)h * NINST + (it + 1) * 16 + ln) * 128 + w * 16 + lg * 4;
      *(float4*)sp = (float4){acc[0], acc[1], acc[2], acc[3]};
    }
  }
}

// ---------------------------------------------------------------------------
// Cross-chunk scan: Sfin -> incoming states, written in Sc' fragment order.
// ---------------------------------------------------------------------------
__global__ __launch_bounds__(256) void scanB_kernel(const float* __restrict__ P,
                                                    const float* __restrict__ Sfin,
                                                    unsigned short* __restrict__ Sc) {
  int t = blockIdx.x * 256 + threadIdx.x;
  if (t >= BH * NHD) return;
  int n = t & 31, h = (t >> 5) & 255, b = t >> 13;
  float wlr = P[6*HN + h*NHD + n], wli = P[7*HN + h*NHD + n];
  unsigned* sc = (unsigned*)Sc;
  {
    int k = 2 * n;
    int ks = k >> 5, lg = (k & 31) >> 3, eh = (k & 7) >> 1;
    float ar = 0.f, ai = 0.f;
    for (int g = 0; g < NG; ++g) {
      int inst = b * NG + g;
      int it = inst >> 4, ln = inst & 15;
      size_t chunk = (size_t)(h * 32 + it) * 256 + ks * 64 + ln * 4 + lg;
      sc[chunk * 4 + eh] = packbf2(ar, ai);
      const float* sp = Sfin + ((size_t)h * NINST + inst) * 128 + 2 * n;
      float lr = sp[0], li = sp[1];
      float nr = lr + wlr * ar - wli * ai;
      float ni = li + wlr * ai + wli * ar;
      ar = nr; ai = ni;
    }
  }
  {
    int k = 64 + 2 * n;
    int ks = k >> 5, lg = (k & 31) >> 3, eh = (k & 7) >> 1;
    float ar = 0.f, ai = 0.f;
    for (int g = NG - 1; g >= 0; --g) {
      int inst = b * NG + g;
      int it = inst >> 4, ln = inst & 15;
      size_t chunk = (size_t)(h * 32 + it) * 256 + ks * 64 + ln * 4 + lg;
      sc[chunk * 4 + eh] = packbf2(ar, ai);
      const float* sp = Sfin + ((size_t)h * NINST + inst) * 128 + 64 + 2 * n;
      float lr = sp[0], li = sp[1];
      float nr = lr + wlr * ar - wli * ai;
      float ni = li + wlr * ai + wli * ar;
      ar = nr; ai = ni;
    }
  }
}

// ---------------------------------------------------------------------------
// Fused local Toeplitz conv + correction + gelu: y = gelu(T'_h.u + E'_h.Sc).
// Grid 512 = (ihalf, h): 2 blocks/CU -> 4 waves/SIMD. T'_h/E'_h register-
// resident; 2nd read of T'_h/E'_h (other ihalf) L2-hit (same XCD).
// ---------------------------------------------------------------------------
__device__ __forceinline__ void comp_y(const short8 (&Tf)[2][8], const short8 (&Ef)[2][4],
                                       const short8 (&Bf)[8], const short8 (&Sf)[4],
                                       int h, int it, int w, int ln, int lg,
                                       unsigned short* __restrict__ Y2) {
  int inst = it * 16 + ln, bb = inst >> 5, g = inst & 31;
  unsigned short* yrow = Y2 + (size_t)(bb * 256 + h) * LL + g * 256;
  #pragma unroll
  for (int t2 = 0; t2 < 2; ++t2) {
    int tt = w * 2 + t2;
    floatx4 acc = (floatx4){0.f, 0.f, 0.f, 0.f};
    #pragma unroll
    for (int ks = 0; ks < 8; ++ks)
      acc = __builtin_amdgcn_mfma_f32_16x16x32_bf16(Tf[t2][ks], Bf[ks], acc, 0, 0, 0);
    #pragma unroll
    for (int ks = 0; ks < 4; ++ks)
      acc = __builtin_amdgcn_mfma_f32_16x16x32_bf16(Ef[t2][ks], Sf[ks], acc, 0, 0, 0);
    float y0 = gelu_t(acc[0]), y1 = gelu_t(acc[1]);
    float y2v = gelu_t(acc[2]), y3 = gelu_t(acc[3]);
    uint2 vv; vv.x = packbf2(y0, y1); vv.y = packbf2(y2v, y3);
    *(uint2*)(yrow + tt * 16 + lg * 4) = vv;
  }
}

__global__ __launch_bounds__(512, 2) void yloc_corr(const unsigned short* __restrict__ T,
                                                    const unsigned short* __restrict__ E,
                                                    const unsigned short* __restrict__ Sc,
                                                    const unsigned short* __restrict__ UF,
                                                    unsigned short* __restrict__ Y2) {
  int tid = threadIdx.x, w = tid >> 6, lane = tid & 63;
  int ln = lane & 15, lg = lane >> 4;
  int bid = blockIdx.x;
  int h = bid & 255, itb = (bid >> 8) * 16;
  const short8* T8 = (const short8*)T;
  const short8* E8 = (const short8*)E;
  const short8* S8 = (const short8*)Sc;
  const short8* U8 = (const short8*)UF;

  short8 Tf[2][8], Ef[2][4];
  #pragma unroll
  for (int t2 = 0; t2 < 2; ++t2) {
    int tt = w * 2 + t2;
    size_t tb = (size_t)(h * 16 + tt) * 512 + ln * 4 + lg;
    #pragma unroll
    for (int ks = 0; ks < 8; ++ks) Tf[t2][ks] = T8[tb + ks * 64];
    size_t eb = (size_t)(h * 16 + tt) * 256 + ln * 4 + lg;
    #pragma unroll
    for (int ks = 0; ks < 4; ++ks) Ef[t2][ks] = E8[eb + ks * 64];
  }

  short8 BfA[8], SfA[4], BfB[8], SfB[4];
  load_bu(U8, h, itb, ln, lg, BfA);
  load_bs(S8, h, itb, ln, lg, SfA);

  for (int it = itb; it < itb + 16; it += 2) {
    load_bu(U8, h, it + 1, ln, lg, BfB);
    load_bs(S8, h, it + 1, ln, lg, SfB);
    comp_y(Tf, Ef, BfA, SfA, h, it, w, ln, lg, Y2);
    if (it + 2 < itb + 16) {
      load_bu(U8, h, it + 2, ln, lg, BfA);
      load_bs(S8, h, it + 2, ln, lg, SfA);
    }
    comp_y(Tf, Ef, BfB, SfB, h, it + 1, w, ln, lg, Y2);
  }
}

// ---------------------------------------------------------------------------
// MFMA GEMM + GLU, fused transpose staging (R11 structure); out stores are
// nontemporal (never re-read -> keep L2 for Y2/Wf).
// ---------------------------------------------------------------------------
#define RAW_W 258   // u16 per raw row (+2 pad -> 129-word stride, conflict-lite)
__global__ __launch_bounds__(1024, 4) void gemm_mfma(
    const unsigned short* __restrict__ Wf,
    const unsigned short* __restrict__ Y2,
    const float* __restrict__ bvec, float* __restrict__ out) {
  __shared__ __align__(16) unsigned short ldsB[32768];      // 64 KB frag-order B
  __shared__ unsigned short raw[64 * RAW_W];                // ~33 KB h-major slice
  int tid  = threadIdx.x;
  int w    = tid >> 6;
  int lane = tid & 63;
  int ln = lane & 15, lg = lane >> 4;
  int b  = blockIdx.x >> 6;
  int l0 = (blockIdx.x & 63) << 7;

  const short8* W8 = (const short8*)Wf;

  // --- fused transpose staging: 2 slices of 64 l-columns ---
  #pragma unroll
  for (int sl = 0; sl < 2; ++sl) {
    {
      int h = tid >> 2, lc = tid & 3;   // h 0..255, lc selects 16 l
      const unsigned short* src = Y2 + (((size_t)(b * 256 + h)) << 13) + l0 + sl * 64 + lc * 16;
      short8 v0 = ((const short8*)src)[0];
      short8 v1 = ((const short8*)src)[1];
      #pragma unroll
      for (int e = 0; e < 8; ++e) raw[(lc * 16 + e) * RAW_W + h] = (unsigned short)v0[e];
      #pragma unroll
      for (int e = 0; e < 8; ++e) raw[(lc * 16 + 8 + e) * RAW_W + h] = (unsigned short)v1[e];
    }
    __syncthreads();
    {
      int c = tid & 31, lq = tid >> 5;  // c = h-chunk (8 h), lq 0..31
      #pragma unroll
      for (int s2 = 0; s2 < 2; ++s2) {
        int lpp = lq + s2 * 32;         // l within slice
        int l = sl * 64 + lpp;          // tile row
        short8 vv;
        #pragma unroll
        for (int e = 0; e < 8; ++e) vv[e] = (short)raw[lpp * RAW_W + c * 8 + e];
        ((short8*)ldsB)[l * 32 + (c ^ (l & 7))] = vv;
      }
    }
    __syncthreads();
  }

  // --- compute (identical to proven R10 path) ---
  int mgrp = w >> 1, ngrp = w & 1;
  floatx4 acc[4][4];
  #pragma unroll
  for (int m = 0; m < 4; ++m)
    #pragma unroll
    for (int n = 0; n < 4; ++n) acc[m][n] = (floatx4){0.f, 0.f, 0.f, 0.f};

  const short8* L8 = (const short8*)ldsB;
  #pragma unroll
  for (int ks = 0; ks < 8; ++ks) {
    short8 Bf[4];
    #pragma unroll
    for (int nf = 0; nf < 4; ++nf) {
      int row = ngrp * 64 + nf * 16 + ln;
      Bf[nf] = L8[row * 32 + ((ks * 4 + lg) ^ (row & 7))];
    }
    #pragma unroll
    for (int mm = 0; mm < 4; ++mm) {
      int og = mgrp * 2 + (mm & 1) + (mm >> 1) * 16;     // o-row group /16
      short8 Af = W8[(size_t)(og * 8 + ks) * 64 + ln * 4 + lg];
      #pragma unroll
      for (int nf = 0; nf < 4; ++nf)
        acc[mm][nf] = __builtin_amdgcn_mfma_f32_16x16x32_bf16(Af, Bf[nf], acc[mm][nf], 0, 0, 0);
    }
  }

  #pragma unroll
  for (int mm = 0; mm < 2; ++mm) {
    int obase = mgrp * 32 + mm * 16 + lg * 4;
    #pragma unroll
    for (int r = 0; r < 4; ++r) {
      int o = obase + r;
      float b0 = bvec[o];
      float b1 = bvec[HH + o];
      float* op = out + ((size_t)(b * HH + o)) * LL + l0 + ngrp * 64 + ln;
      #pragma unroll
      for (int nf = 0; nf < 4; ++nf) {
        float z1 = acc[mm][nf][r] + b0;
        float z2 = acc[mm + 2][nf][r] + b1;
        __builtin_nontemporal_store(z1 / (1.f + __expf(-z2)), &op[nf * 16]);
      }
    }
  }
}

// ---------------------------------------------------------------------------
extern "C" void kernel_launch(void* const* d_in, const int* in_sizes, int n_in,
                              void* d_out, int out_size, void* d_ws, size_t ws_size,
                              hipStream_t stream) {
  const float* x      = (const float*)d_in[0];
  const float* log_dt = (const float*)d_in[1];
  const float* A_real = (const float*)d_in[2];
  const float* A_imag = (const float*)d_in[3];
  const float* C_real = (const float*)d_in[4];
  const float* C_imag = (const float*)d_in[5];
  const float* Dv     = (const float*)d_in[6];
  const float* W      = (const float*)d_in[7];
  const float* bvec   = (const float*)d_in[8];
  float* out = (float*)d_out;

  // d_out doubles as scratch for Sfin only (serial: sfin writes -> scanB reads
  // -> gemm overwrites all of d_out last):
  float* Sfin = (float*)d_out + 16777216;   // d_out[64:128MiB)

  // ws: all regions dedicated (no aliasing). Total 226 MiB.
  char* ws = (char*)d_ws;
  float*          P  = (float*)ws;                          // 320 KB
  unsigned short* Wf = (unsigned short*)(ws + 524288);      // 256 KB
  float*          Kf = (float*)(ws + 786432);               // 256 KB
  float*          Kb = (float*)(ws + 1048576);              // 256 KB
  size_t OFF_UF = (size_t)2 << 20;                          // [2, 66) MiB
  size_t OFF_T  = OFF_UF + ((size_t)256 * 32 * 512 * 16);   // [66, 98) MiB
  size_t OFF_E  = OFF_T + ((size_t)256 * 16 * 512 * 16);    // [98, 114) MiB
  size_t OFF_V  = OFF_E + ((size_t)256 * 16 * 256 * 16);    // [114, 130) MiB
  size_t OFF_SC = OFF_V + ((size_t)256 * 8 * 512 * 16);     // [130, 162) MiB
  size_t OFF_Y2 = OFF_SC + ((size_t)256 * 32 * 256 * 16);   // [162, 226) MiB
  unsigned short* UF = (unsigned short*)(ws + OFF_UF);
  unsigned short* T  = (unsigned short*)(ws + OFF_T);
  unsigned short* E  = (unsigned short*)(ws + OFF_E);
  unsigned short* V  = (unsigned short*)(ws + OFF_V);
  unsigned short* Sc = (unsigned short*)(ws + OFF_SC);
  unsigned short* Y2 = (unsigned short*)(ws + OFF_Y2);

  precomp_kernel<<<HN / 256, 256, 0, stream>>>(log_dt, A_real, A_imag, C_real, C_imag, P);
  wt_frag_kernel<<<32, 256, 0, stream>>>(W, Wf);
  kprep_kernel<<<HH * 256 / 256, 256, 0, stream>>>(P, Kf, Kb);
  tprep_kernel<<<dim3(HH, 16), 256, 0, stream>>>(Kf, Kb, Dv, T);
  eprep_kernel<<<dim3(HH, 16), 256, 0, stream>>>(P, E);
  vprep_kernel<<<dim3(HH, 8), 256, 0, stream>>>(P, V);
  transpose_kernel<<<dim3(BB, LL / 32), 256, 0, stream>>>(x, UF);
  sfin_mfma<<<2 * HH, 512, 0, stream>>>(V, UF, Sfin);
  scanB_kernel<<<(BH * NHD) / 256, 256, 0, stream>>>(P, Sfin, Sc);
  yloc_corr<<<2 * HH, 512, 0, stream>>>(T, E, Sc, UF, Y2);
  gemm_mfma<<<BB * (LL / 128), 1024, 0, stream>>>(Wf, Y2, bvec, out);
}

// Round 14
// 293.085 us; speedup vs baseline: 1.0789x; 1.0789x over previous
//
#include <hip/hip_runtime.h>
#include <hip/hip_bf16.h>
#include <math.h>

#define HH  256      // d_model
#define NHD 32       // state halves
#define LL  8192     // sequence length
#define BB  16       // batch
#define HN  (HH*NHD) // 8192
#define BH  (BB*HH)  // 4096
#define LC  256      // chunk length
#define NG  (LL/LC)  // 32 chunks per row
#define NINST (BB*NG) // 512 chunk instances per h

typedef __attribute__((ext_vector_type(8))) short short8;
typedef __attribute__((ext_vector_type(4))) float floatx4;

__device__ __forceinline__ unsigned short f2bf(float f) {
  unsigned u = __float_as_uint(f);
  unsigned r = (u + 0x7FFF + ((u >> 16) & 1)) >> 16;
  return (unsigned short)r;
}
__device__ __forceinline__ float bf2f(unsigned short s) {
  return __uint_as_float((unsigned)s << 16);
}
__device__ __forceinline__ unsigned packbf2(float a, float b) {
  return (unsigned)f2bf(a) | ((unsigned)f2bf(b) << 16);
}
__device__ __forceinline__ float gelu_t(float y) {
  float y2 = y * y;
  float arg = 1.5957691216f * fmaf(0.044715f * y2, y, y);
  return y / (1.f + __expf(-arg));
}

// ---------------------------------------------------------------------------
// Param precompute. P[k*HN + h*NHD + n]:
// 0=wr 1=wi 2=c0r 3=c0i 4=c1r 5=c1i 6=wLr 7=wLi 8=ar(dtA re) 9=ai(dtA im)
// ---------------------------------------------------------------------------
__global__ void precomp_kernel(const float* __restrict__ log_dt,
                               const float* __restrict__ A_real,
                               const float* __restrict__ A_imag,
                               const float* __restrict__ C_real,
                               const float* __restrict__ C_imag,
                               float* __restrict__ P) {
  int i = blockIdx.x * blockDim.x + threadIdx.x;
  if (i >= HN) return;
  int h = i >> 5;
  double dt  = exp((double)log_dt[h]);
  double Are = -exp((double)A_real[i]);
  double Aim = (double)A_imag[i];
  double ar = Are * dt, ai = Aim * dt;
  double ea = exp(ar);
  double wr = ea * cos(ai), wi = ea * sin(ai);
  double em_r = wr - 1.0, em_i = wi;
  double den = Are * Are + Aim * Aim;
  double rr = (em_r * Are + em_i * Aim) / den;
  double ri = (em_i * Are - em_r * Aim) / den;
  P[0*HN + i] = (float)wr;
  P[1*HN + i] = (float)wi;
  {
    double cr = (double)C_real[i], ci = (double)C_imag[i];
    P[2*HN + i] = (float)(2.0 * (cr * rr - ci * ri));
    P[3*HN + i] = (float)(2.0 * (cr * ri + ci * rr));
  }
  {
    double cr = (double)C_real[HN + i], ci = (double)C_imag[HN + i];
    P[4*HN + i] = (float)(2.0 * (cr * rr - ci * ri));
    P[5*HN + i] = (float)(2.0 * (cr * ri + ci * rr));
  }
  {
    double arL = ar * (double)LC, aiL = ai * (double)LC;
    double eaL = exp(arL);
    P[6*HN + i] = (float)(eaL * cos(aiL));
    P[7*HN + i] = (float)(eaL * sin(aiL));
  }
  P[8*HN + i] = (float)ar;
  P[9*HN + i] = (float)ai;
}

// ---------------------------------------------------------------------------
// W (512,256) f32 -> Wf fragment-order bf16:
// chunk ((og*8+ks)*16+ln)*4+lg holds W[og*16+ln][ks*32+lg*8+e], e in [0,8).
// ---------------------------------------------------------------------------
__global__ __launch_bounds__(256) void wt_frag_kernel(const float* __restrict__ W,
                                                      unsigned short* __restrict__ Wf) {
  int og = blockIdx.x;                       // 0..31
  #pragma unroll
  for (int i = 0; i < 2; ++i) {
    int j = i * 256 + threadIdx.x;           // 0..511 = ks*64 + ln*4 + lg
    int ks = j >> 6, ln = (j >> 2) & 15, lg = j & 3;
    const float* src = W + (size_t)(og * 16 + ln) * 256 + ks * 32 + lg * 8;
    short8 vv;
    #pragma unroll
    for (int e = 0; e < 8; ++e) vv[e] = (short)f2bf(src[e]);
    ((short8*)Wf)[og * 512 + j] = vv;
  }
}

// ---------------------------------------------------------------------------
// kf/kb tables: kf[h][d] = sum_n Re(c0_n w_n^d), kb same with c1.
// ---------------------------------------------------------------------------
__global__ __launch_bounds__(256) void kprep_kernel(const float* __restrict__ P,
                                                    float* __restrict__ Kf,
                                                    float* __restrict__ Kb) {
  int i = blockIdx.x * 256 + threadIdx.x;   // h*256 + d
  int d = i & 255, h = i >> 8;
  float fd = (float)d;
  float sf = 0.f, sb = 0.f;
  #pragma unroll 4
  for (int n = 0; n < NHD; ++n) {
    int j = h * NHD + n;
    float m  = __expf(fd * P[8*HN + j]);
    float ph = fd * P[9*HN + j];
    float cs = cosf(ph), sn = sinf(ph);
    float re = m * cs, im = m * sn;
    sf += P[2*HN + j] * re - P[3*HN + j] * im;
    sb += P[4*HN + j] * re - P[5*HN + j] * im;
  }
  Kf[i] = sf;
  Kb[i] = sb;
}

// ---------------------------------------------------------------------------
// T' fragment-order: chunk idx (((h*16+tt)*8+ks)*16+ln)*4+lg holds
// T[t=tt*16+ln][s=ks*32+lg*8+e], e in [0,8).
// ---------------------------------------------------------------------------
__global__ __launch_bounds__(256) void tprep_kernel(const float* __restrict__ Kf,
                                                    const float* __restrict__ Kb,
                                                    const float* __restrict__ Dv,
                                                    unsigned short* __restrict__ T) {
  int h = blockIdx.x, tt = blockIdx.y;
  const float* kf = Kf + h * 256;
  const float* kb = Kb + h * 256;
  float dh = Dv[h];
  short8* out = (short8*)T;
  #pragma unroll
  for (int i = 0; i < 2; ++i) {
    int j = i * 256 + threadIdx.x;          // 0..511 = ks*64 + ln*4 + lg
    int ks = j >> 6, ln = (j >> 2) & 15, lg = j & 3;
    int t = tt * 16 + ln;
    short8 vv;
    #pragma unroll
    for (int e = 0; e < 8; ++e) {
      int s = ks * 32 + lg * 8 + e;
      int d = t - s;
      float v = (d > 0) ? kf[d] : ((d < 0) ? kb[-d - 1] : (kf[0] + dh));
      vv[e] = (short)f2bf(v);
    }
    out[(size_t)(h * 16 + tt) * 512 + j] = vv;
  }
}

// ---------------------------------------------------------------------------
// E' fragment-order: chunk (((h*16+tt)*4+ks)*16+ln)*4+lg holds E[t][k],
// t=tt*16+ln, k=ks*32+lg*8+e. k<64: pairs (Re, -Im) of c0*w^{t+1};
// k>=64: pairs of c1*w^{LC-1-t}. Direct exp.
// ---------------------------------------------------------------------------
__global__ __launch_bounds__(256) void eprep_kernel(const float* __restrict__ P,
                                                    unsigned short* __restrict__ E) {
  int h = blockIdx.x, tt = blockIdx.y;
  int j = threadIdx.x;                       // 0..255 = ks*64 + ln*4 + lg
  int ks = j >> 6, ln = (j >> 2) & 15, lg = j & 3;
  int t = tt * 16 + ln;
  int k0 = ks * 32 + lg * 8;
  short8 vv;
  if (k0 < 64) {
    float d = (float)(t + 1);
    #pragma unroll
    for (int q = 0; q < 4; ++q) {
      int n = (k0 >> 1) + q;
      int idx = h * NHD + n;
      float m  = __expf(d * P[8*HN + idx]);
      float ph = d * P[9*HN + idx];
      float re = m * cosf(ph), im = m * sinf(ph);
      float cr = P[2*HN + idx], ci = P[3*HN + idx];
      float zr = cr * re - ci * im;
      float zi = cr * im + ci * re;
      vv[2*q]   = (short)f2bf(zr);
      vv[2*q+1] = (short)f2bf(-zi);
    }
  } else {
    float d = (float)(LC - 1 - t);
    #pragma unroll
    for (int q = 0; q < 4; ++q) {
      int n = ((k0 - 64) >> 1) + q;
      int idx = h * NHD + n;
      float m  = __expf(d * P[8*HN + idx]);
      float ph = d * P[9*HN + idx];
      float re = m * cosf(ph), im = m * sinf(ph);
      float cr = P[4*HN + idx], ci = P[5*HN + idx];
      float zr = cr * re - ci * im;
      float zi = cr * im + ci * re;
      vv[2*q]   = (short)f2bf(zr);
      vv[2*q+1] = (short)f2bf(-zi);
    }
  }
  ((short8*)E)[(size_t)(h * 16 + tt) * 256 + j] = vv;
}

// ---------------------------------------------------------------------------
// V' fragment-order: chunk (((h*8+mt)*8+ks)*16+ln)*4+lg, row=mt*16+ln:
// row<64: comp(row&1) of w^{LC-1-s}; row>=64: comp of w^s; s=ks*32+lg*8+e.
// ---------------------------------------------------------------------------
__global__ __launch_bounds__(256) void vprep_kernel(const float* __restrict__ P,
                                                    unsigned short* __restrict__ V) {
  int h = blockIdx.x, mt = blockIdx.y;       // mt in [0,8)
  #pragma unroll
  for (int i = 0; i < 2; ++i) {
    int j = i * 256 + threadIdx.x;           // 0..511
    int ks = j >> 6, ln = (j >> 2) & 15, lg = j & 3;
    int row = mt * 16 + ln;
    int dir = row >> 6, nc = row & 63;
    int n = nc >> 1, comp = nc & 1;
    int idx = h * NHD + n;
    float arn = P[8*HN + idx], ain = P[9*HN + idx];
    short8 vv;
    #pragma unroll
    for (int e = 0; e < 8; ++e) {
      int s = ks * 32 + lg * 8 + e;
      float d = (float)(dir ? s : (LC - 1 - s));
      float m = __expf(d * arn);
      float ph = d * ain;
      float v = m * (comp ? sinf(ph) : cosf(ph));
      vv[e] = (short)f2bf(v);
    }
    ((short8*)V)[(size_t)(h * 8 + mt) * 512 + j] = vv;
  }
}

// ---------------------------------------------------------------------------
// x (L,B,H) f32 -> UF fragment-order bf16: chunk (((h*32+it)*8+ks)*16+ln)*4+lg
// = u[b][h][l = g*256 + ks*32 + lg*8 + e], inst = b*32+g = it*16+ln.
// ---------------------------------------------------------------------------
__global__ __launch_bounds__(256) void transpose_kernel(const float* __restrict__ x,
                                                        unsigned short* __restrict__ UF) {
  __shared__ unsigned short tile[32][264];
  int b  = blockIdx.x;
  int lb = blockIdx.y * 32;
  int tid = threadIdx.x;
  int g = lb >> 8, ks = (lb & 255) >> 5;
  int inst = b * 32 + g, it = inst >> 4, lnw = inst & 15;
  #pragma unroll
  for (int i = 0; i < 8; ++i) {
    int idx = i * 256 + tid;                 // 0..2047
    int row = idx >> 6, c4 = idx & 63;
    float4 v = *(const float4*)(x + (size_t)(lb + row) * BH + b * 256 + c4 * 4);
    ushort4 u4v;
    u4v.x = f2bf(v.x); u4v.y = f2bf(v.y); u4v.z = f2bf(v.z); u4v.w = f2bf(v.w);
    *(ushort4*)&tile[row][c4 * 4] = u4v;
  }
  __syncthreads();
  short8* out = (short8*)UF;
  #pragma unroll
  for (int i = 0; i < 4; ++i) {
    int j = i * 256 + tid;                   // 0..1023
    int h = j >> 2, lg = j & 3;
    short8 vv;
    #pragma unroll
    for (int e = 0; e < 8; ++e) vv[e] = (short)tile[lg * 8 + e][h];
    out[(size_t)(h * 32 + it) * 512 + ks * 64 + lnw * 4 + lg] = vv;
  }
}

// ---------------------------------------------------------------------------
// B-fragment loaders (shared by sfin / yloc): contiguous 1KB wave-loads.
// ---------------------------------------------------------------------------
__device__ __forceinline__ void load_bu(const short8* __restrict__ U8, int h, int it,
                                        int ln, int lg, short8 (&Bf)[8]) {
  size_t ub = (size_t)(h * 32 + it) * 512 + ln * 4 + lg;
  #pragma unroll
  for (int ks = 0; ks < 8; ++ks) Bf[ks] = U8[ub + ks * 64];
}
__device__ __forceinline__ void load_bs(const short8* __restrict__ S8, int h, int it,
                                        int ln, int lg, short8 (&Sf)[4]) {
  size_t sb = (size_t)(h * 32 + it) * 256 + ln * 4 + lg;
  #pragma unroll
  for (int ks = 0; ks < 4; ++ks) Sf[ks] = S8[sb + ks * 64];
}

// ---------------------------------------------------------------------------
// Chunk-final states: Sfin[h][inst][k] bf16 = V'_h . u.
// ONE block per h (grid 256, 512 thr / 8 waves; R11-proven shape).
// ---------------------------------------------------------------------------
__global__ __launch_bounds__(512, 2) void sfin_mfma(const unsigned short* __restrict__ V,
                                                    const unsigned short* __restrict__ UF,
                                                    unsigned short* __restrict__ Sfin) {
  int tid = threadIdx.x, w = tid >> 6, lane = tid & 63;
  int ln = lane & 15, lg = lane >> 4;
  int h = blockIdx.x;
  const short8* U8 = (const short8*)UF;
  const short8* V8 = (const short8*)V;

  short8 Vf[8];
  size_t vb = (size_t)(h * 8 + w) * 512 + ln * 4 + lg;
  #pragma unroll
  for (int ks = 0; ks < 8; ++ks) Vf[ks] = V8[vb + ks * 64];

  short8 BfA[8], BfB[8];
  load_bu(U8, h, 0, ln, lg, BfA);

  for (int it = 0; it < 32; it += 2) {
    load_bu(U8, h, it + 1, ln, lg, BfB);
    {
      floatx4 acc = (floatx4){0.f, 0.f, 0.f, 0.f};
      #pragma unroll
      for (int ks = 0; ks < 8; ++ks)
        acc = __builtin_amdgcn_mfma_f32_16x16x32_bf16(Vf[ks], BfA[ks], acc, 0, 0, 0);
      unsigned short* sp = Sfin + ((size_t)h * NINST + it * 16 + ln) * 128 + w * 16 + lg * 4;
      uint2 pv; pv.x = packbf2(acc[0], acc[1]); pv.y = packbf2(acc[2], acc[3]);
      *(uint2*)sp = pv;
    }
    if (it + 2 < 32) load_bu(U8, h, it + 2, ln, lg, BfA);
    {
      floatx4 acc = (floatx4){0.f, 0.f, 0.f, 0.f};
      #pragma unroll
      for (int ks = 0; ks < 8; ++ks)
        acc = __builtin_amdgcn_mfma_f32_16x16x32_bf16(Vf[ks], BfB[ks], acc, 0, 0, 0);
      unsigned short* sp = Sfin + ((size_t)h * NINST + (it + 1) * 16 + ln) * 128 + w * 16 + lg * 4;
      uint2 pv; pv.x = packbf2(acc[0], acc[1]); pv.y = packbf2(acc[2], acc[3]);
      *(uint2*)sp = pv;
    }
  }
}

// ---------------------------------------------------------------------------
// Cross-chunk scan: Sfin (bf16) -> incoming states, Sc' fragment order.
// ---------------------------------------------------------------------------
__global__ __launch_bounds__(256) void scanB_kernel(const float* __restrict__ P,
                                                    const unsigned short* __restrict__ Sfin,
                                                    unsigned short* __restrict__ Sc) {
  int t = blockIdx.x * 256 + threadIdx.x;
  if (t >= BH * NHD) return;
  int n = t & 31, h = (t >> 5) & 255, b = t >> 13;
  float wlr = P[6*HN + h*NHD + n], wli = P[7*HN + h*NHD + n];
  unsigned* sc = (unsigned*)Sc;
  {
    int k = 2 * n;
    int ks = k >> 5, lg = (k & 31) >> 3, eh = (k & 7) >> 1;
    float ar = 0.f, ai = 0.f;
    for (int g = 0; g < NG; ++g) {
      int inst = b * NG + g;
      int it = inst >> 4, ln = inst & 15;
      size_t chunk = (size_t)(h * 32 + it) * 256 + ks * 64 + ln * 4 + lg;
      sc[chunk * 4 + eh] = packbf2(ar, ai);
      const unsigned short* sp = Sfin + ((size_t)h * NINST + inst) * 128 + 2 * n;
      float lr = bf2f(sp[0]), li = bf2f(sp[1]);
      float nr = lr + wlr * ar - wli * ai;
      float ni = li + wlr * ai + wli * ar;
      ar = nr; ai = ni;
    }
  }
  {
    int k = 64 + 2 * n;
    int ks = k >> 5, lg = (k & 31) >> 3, eh = (k & 7) >> 1;
    float ar = 0.f, ai = 0.f;
    for (int g = NG - 1; g >= 0; --g) {
      int inst = b * NG + g;
      int it = inst >> 4, ln = inst & 15;
      size_t chunk = (size_t)(h * 32 + it) * 256 + ks * 64 + ln * 4 + lg;
      sc[chunk * 4 + eh] = packbf2(ar, ai);
      const unsigned short* sp = Sfin + ((size_t)h * NINST + inst) * 128 + 64 + 2 * n;
      float lr = bf2f(sp[0]), li = bf2f(sp[1]);
      float nr = lr + wlr * ar - wli * ai;
      float ni = li + wlr * ai + wli * ar;
      ar = nr; ai = ni;
    }
  }
}

// ---------------------------------------------------------------------------
// Fused local Toeplitz conv + correction + gelu: y = gelu(T'_h.u + E'_h.Sc).
// ONE block per h (grid 256, 512 thr / 8 waves; R11-proven shape).
// ---------------------------------------------------------------------------
__device__ __forceinline__ void comp_y(const short8 (&Tf)[2][8], const short8 (&Ef)[2][4],
                                       const short8 (&Bf)[8], const short8 (&Sf)[4],
                                       int h, int it, int w, int ln, int lg,
                                       unsigned short* __restrict__ Y2) {
  int inst = it * 16 + ln, bb = inst >> 5, g = inst & 31;
  unsigned short* yrow = Y2 + (size_t)(bb * 256 + h) * LL + g * 256;
  #pragma unroll
  for (int t2 = 0; t2 < 2; ++t2) {
    int tt = w * 2 + t2;
    floatx4 acc = (floatx4){0.f, 0.f, 0.f, 0.f};
    #pragma unroll
    for (int ks = 0; ks < 8; ++ks)
      acc = __builtin_amdgcn_mfma_f32_16x16x32_bf16(Tf[t2][ks], Bf[ks], acc, 0, 0, 0);
    #pragma unroll
    for (int ks = 0; ks < 4; ++ks)
      acc = __builtin_amdgcn_mfma_f32_16x16x32_bf16(Ef[t2][ks], Sf[ks], acc, 0, 0, 0);
    float y0 = gelu_t(acc[0]), y1 = gelu_t(acc[1]);
    float y2v = gelu_t(acc[2]), y3 = gelu_t(acc[3]);
    uint2 vv; vv.x = packbf2(y0, y1); vv.y = packbf2(y2v, y3);
    *(uint2*)(yrow + tt * 16 + lg * 4) = vv;
  }
}

__global__ __launch_bounds__(512, 2) void yloc_corr(const unsigned short* __restrict__ T,
                                                    const unsigned short* __restrict__ E,
                                                    const unsigned short* __restrict__ Sc,
                                                    const unsigned short* __restrict__ UF,
                                                    unsigned short* __restrict__ Y2) {
  int tid = threadIdx.x, w = tid >> 6, lane = tid & 63;
  int ln = lane & 15, lg = lane >> 4;
  int h = blockIdx.x;
  const short8* T8 = (const short8*)T;
  const short8* E8 = (const short8*)E;
  const short8* S8 = (const short8*)Sc;
  const short8* U8 = (const short8*)UF;

  short8 Tf[2][8], Ef[2][4];
  #pragma unroll
  for (int t2 = 0; t2 < 2; ++t2) {
    int tt = w * 2 + t2;
    size_t tb = (size_t)(h * 16 + tt) * 512 + ln * 4 + lg;
    #pragma unroll
    for (int ks = 0; ks < 8; ++ks) Tf[t2][ks] = T8[tb + ks * 64];
    size_t eb = (size_t)(h * 16 + tt) * 256 + ln * 4 + lg;
    #pragma unroll
    for (int ks = 0; ks < 4; ++ks) Ef[t2][ks] = E8[eb + ks * 64];
  }

  short8 BfA[8], SfA[4], BfB[8], SfB[4];
  load_bu(U8, h, 0, ln, lg, BfA);
  load_bs(S8, h, 0, ln, lg, SfA);

  for (int it = 0; it < 32; it += 2) {
    load_bu(U8, h, it + 1, ln, lg, BfB);
    load_bs(S8, h, it + 1, ln, lg, SfB);
    comp_y(Tf, Ef, BfA, SfA, h, it, w, ln, lg, Y2);
    if (it + 2 < 32) {
      load_bu(U8, h, it + 2, ln, lg, BfA);
      load_bs(S8, h, it + 2, ln, lg, SfA);
    }
    comp_y(Tf, Ef, BfB, SfB, h, it + 1, w, ln, lg, Y2);
  }
}

// ---------------------------------------------------------------------------
// MFMA GEMM + GLU, fused transpose staging; BN=64 half-tiles, 512 thr,
// LDS 48.1 KB -> 3 blocks/CU so staging overlaps other blocks' compute.
// ---------------------------------------------------------------------------
#define RAW_W 258   // u16 per raw row (+2 pad)
__global__ __launch_bounds__(512, 4) void gemm_mfma(
    const unsigned short* __restrict__ Wf,
    const unsigned short* __restrict__ Y2,
    const float* __restrict__ bvec, float* __restrict__ out) {
  __shared__ __align__(16) unsigned short ldsB[16384];      // 32 KB: 64 rows x 32 chunks
  __shared__ unsigned short raw[32 * RAW_W];                // 16.1 KB h-major slice
  int tid  = threadIdx.x;
  int w    = tid >> 6;
  int lane = tid & 63;
  int ln = lane & 15, lg = lane >> 4;
  int b  = blockIdx.x >> 7;
  int l0 = (blockIdx.x & 127) << 6;

  const short8* W8 = (const short8*)Wf;

  // --- fused transpose staging: 2 slices of 32 l-columns ---
  #pragma unroll
  for (int sl = 0; sl < 2; ++sl) {
    {
      int h = tid >> 1, lc = tid & 1;   // h 0..255, lc selects 16 l
      const unsigned short* src = Y2 + (((size_t)(b * 256 + h)) << 13) + l0 + sl * 32 + lc * 16;
      short8 v0 = ((const short8*)src)[0];
      short8 v1 = ((const short8*)src)[1];
      #pragma unroll
      for (int e = 0; e < 8; ++e) raw[(lc * 16 + e) * RAW_W + h] = (unsigned short)v0[e];
      #pragma unroll
      for (int e = 0; e < 8; ++e) raw[(lc * 16 + 8 + e) * RAW_W + h] = (unsigned short)v1[e];
    }
    __syncthreads();
    {
      int c = tid & 31, lq = tid >> 5;  // c = h-chunk (8 h), lq 0..15
      #pragma unroll
      for (int s2 = 0; s2 < 2; ++s2) {
        int lpp = lq + s2 * 16;         // l within slice (0..31)
        int l = sl * 32 + lpp;          // tile row (0..63)
        short8 vv;
        #pragma unroll
        for (int e = 0; e < 8; ++e) vv[e] = (short)raw[lpp * RAW_W + c * 8 + e];
        ((short8*)ldsB)[l * 32 + (c ^ (l & 7))] = vv;
      }
    }
    __syncthreads();
  }

  // --- compute: wave w owns o-rows {w*32..+32} u {256+w*32..+32}, all 64 cols ---
  floatx4 acc[4][4];
  #pragma unroll
  for (int m = 0; m < 4; ++m)
    #pragma unroll
    for (int n = 0; n < 4; ++n) acc[m][n] = (floatx4){0.f, 0.f, 0.f, 0.f};

  const short8* L8 = (const short8*)ldsB;
  #pragma unroll
  for (int ks = 0; ks < 8; ++ks) {
    short8 Bf[4];
    #pragma unroll
    for (int nf = 0; nf < 4; ++nf) {
      int row = nf * 16 + ln;
      Bf[nf] = L8[row * 32 + ((ks * 4 + lg) ^ (row & 7))];
    }
    #pragma unroll
    for (int mm = 0; mm < 4; ++mm) {
      int og = w * 2 + (mm & 1) + (mm >> 1) * 16;        // o-row group /16
      short8 Af = W8[(size_t)(og * 8 + ks) * 64 + ln * 4 + lg];
      #pragma unroll
      for (int nf = 0; nf < 4; ++nf)
        acc[mm][nf] = __builtin_amdgcn_mfma_f32_16x16x32_bf16(Af, Bf[nf], acc[mm][nf], 0, 0, 0);
    }
  }

  #pragma unroll
  for (int mm = 0; mm < 2; ++mm) {
    int obase = w * 32 + mm * 16 + lg * 4;
    #pragma unroll
    for (int r = 0; r < 4; ++r) {
      int o = obase + r;
      float b0 = bvec[o];
      float b1 = bvec[HH + o];
      float* op = out + ((size_t)(b * HH + o)) * LL + l0 + ln;
      #pragma unroll
      for (int nf = 0; nf < 4; ++nf) {
        float z1 = acc[mm][nf][r] + b0;
        float z2 = acc[mm + 2][nf][r] + b1;
        op[nf * 16] = z1 / (1.f + __expf(-z2));
      }
    }
  }
}

// ---------------------------------------------------------------------------
extern "C" void kernel_launch(void* const* d_in, const int* in_sizes, int n_in,
                              void* d_out, int out_size, void* d_ws, size_t ws_size,
                              hipStream_t stream) {
  const float* x      = (const float*)d_in[0];
  const float* log_dt = (const float*)d_in[1];
  const float* A_real = (const float*)d_in[2];
  const float* A_imag = (const float*)d_in[3];
  const float* C_real = (const float*)d_in[4];
  const float* C_imag = (const float*)d_in[5];
  const float* Dv     = (const float*)d_in[6];
  const float* W      = (const float*)d_in[7];
  const float* bvec   = (const float*)d_in[8];
  float* out = (float*)d_out;

  // d_out doubles as scratch for Sfin only (bf16, 33.5 MB at [64:97.5MiB);
  // serial: sfin writes -> scanB reads -> gemm overwrites all of d_out last):
  unsigned short* Sfin = (unsigned short*)d_out + 33554432;

  // ws: all regions dedicated (no aliasing). Total 226 MiB.
  char* ws = (char*)d_ws;
  float*          P  = (float*)ws;                          // 320 KB
  unsigned short* Wf = (unsigned short*)(ws + 524288);      // 256 KB
  float*          Kf = (float*)(ws + 786432);               // 256 KB
  float*          Kb = (float*)(ws + 1048576);              // 256 KB
  size_t OFF_UF = (size_t)2 << 20;                          // [2, 66) MiB
  size_t OFF_T  = OFF_UF + ((size_t)256 * 32 * 512 * 16);   // [66, 98) MiB
  size_t OFF_E  = OFF_T + ((size_t)256 * 16 * 512 * 16);    // [98, 114) MiB
  size_t OFF_V  = OFF_E + ((size_t)256 * 16 * 256 * 16);    // [114, 130) MiB
  size_t OFF_SC = OFF_V + ((size_t)256 * 8 * 512 * 16);     // [130, 162) MiB
  size_t OFF_Y2 = OFF_SC + ((size_t)256 * 32 * 256 * 16);   // [162, 226) MiB
  unsigned short* UF = (unsigned short*)(ws + OFF_UF);
  unsigned short* T  = (unsigned short*)(ws + OFF_T);
  unsigned short* E  = (unsigned short*)(ws + OFF_E);
  unsigned short* V  = (unsigned short*)(ws + OFF_V);
  unsigned short* Sc = (unsigned short*)(ws + OFF_SC);
  unsigned short* Y2 = (unsigned short*)(ws + OFF_Y2);

  precomp_kernel<<<HN / 256, 256, 0, stream>>>(log_dt, A_real, A_imag, C_real, C_imag, P);
  wt_frag_kernel<<<32, 256, 0, stream>>>(W, Wf);
  kprep_kernel<<<HH * 256 / 256, 256, 0, stream>>>(P, Kf, Kb);
  tprep_kernel<<<dim3(HH, 16), 256, 0, stream>>>(Kf, Kb, Dv, T);
  eprep_kernel<<<dim3(HH, 16), 256, 0, stream>>>(P, E);
  vprep_kernel<<<dim3(HH, 8), 256, 0, stream>>>(P, V);
  transpose_kernel<<<dim3(BB, LL / 32), 256, 0, stream>>>(x, UF);
  sfin_mfma<<<HH, 512, 0, stream>>>(V, UF, Sfin);
  scanB_kernel<<<(BH * NHD) / 256, 256, 0, stream>>>(P, Sfin, Sc);
  yloc_corr<<<HH, 512, 0, stream>>>(T, E, Sc, UF, Y2);
  gemm_mfma<<<BB * (LL / 64), 512, 0, stream>>>(Wf, Y2, bvec, out);
}

// Round 15
// 285.299 us; speedup vs baseline: 1.1084x; 1.0273x over previous
//
#include <hip/hip_runtime.h>
#include <hip/hip_bf16.h>
#include <math.h>

#define HH  256      // d_model
#define NHD 32       // state halves
#define LL  8192     // sequence length
#define BB  16       // batch
#define HN  (HH*NHD) // 8192
#define BH  (BB*HH)  // 4096
#define LC  256      // chunk length
#define NG  (LL/LC)  // 32 chunks per row
#define NINST (BB*NG) // 512 chunk instances per h

typedef __attribute__((ext_vector_type(8))) short short8;
typedef __attribute__((ext_vector_type(4))) float floatx4;

__device__ __forceinline__ unsigned short f2bf(float f) {
  unsigned u = __float_as_uint(f);
  unsigned r = (u + 0x7FFF + ((u >> 16) & 1)) >> 16;
  return (unsigned short)r;
}
__device__ __forceinline__ float bf2f(unsigned short s) {
  return __uint_as_float((unsigned)s << 16);
}
__device__ __forceinline__ unsigned packbf2(float a, float b) {
  return (unsigned)f2bf(a) | ((unsigned)f2bf(b) << 16);
}
__device__ __forceinline__ float gelu_t(float y) {
  float y2 = y * y;
  float arg = 1.5957691216f * fmaf(0.044715f * y2, y, y);
  return y / (1.f + __expf(-arg));
}

// ---------------------------------------------------------------------------
// Param precompute. P[k*HN + h*NHD + n]:
// 0=wr 1=wi 2=c0r 3=c0i 4=c1r 5=c1i 6=wLr 7=wLi 8=ar(dtA re) 9=ai(dtA im)
// ---------------------------------------------------------------------------
__global__ void precomp_kernel(const float* __restrict__ log_dt,
                               const float* __restrict__ A_real,
                               const float* __restrict__ A_imag,
                               const float* __restrict__ C_real,
                               const float* __restrict__ C_imag,
                               float* __restrict__ P) {
  int i = blockIdx.x * blockDim.x + threadIdx.x;
  if (i >= HN) return;
  int h = i >> 5;
  double dt  = exp((double)log_dt[h]);
  double Are = -exp((double)A_real[i]);
  double Aim = (double)A_imag[i];
  double ar = Are * dt, ai = Aim * dt;
  double ea = exp(ar);
  double wr = ea * cos(ai), wi = ea * sin(ai);
  double em_r = wr - 1.0, em_i = wi;
  double den = Are * Are + Aim * Aim;
  double rr = (em_r * Are + em_i * Aim) / den;
  double ri = (em_i * Are - em_r * Aim) / den;
  P[0*HN + i] = (float)wr;
  P[1*HN + i] = (float)wi;
  {
    double cr = (double)C_real[i], ci = (double)C_imag[i];
    P[2*HN + i] = (float)(2.0 * (cr * rr - ci * ri));
    P[3*HN + i] = (float)(2.0 * (cr * ri + ci * rr));
  }
  {
    double cr = (double)C_real[HN + i], ci = (double)C_imag[HN + i];
    P[4*HN + i] = (float)(2.0 * (cr * rr - ci * ri));
    P[5*HN + i] = (float)(2.0 * (cr * ri + ci * rr));
  }
  {
    double arL = ar * (double)LC, aiL = ai * (double)LC;
    double eaL = exp(arL);
    P[6*HN + i] = (float)(eaL * cos(aiL));
    P[7*HN + i] = (float)(eaL * sin(aiL));
  }
  P[8*HN + i] = (float)ar;
  P[9*HN + i] = (float)ai;
}

// ---------------------------------------------------------------------------
// W (512,256) f32 -> Wf fragment-order bf16.
// ---------------------------------------------------------------------------
__global__ __launch_bounds__(256) void wt_frag_kernel(const float* __restrict__ W,
                                                      unsigned short* __restrict__ Wf) {
  int og = blockIdx.x;                       // 0..31
  #pragma unroll
  for (int i = 0; i < 2; ++i) {
    int j = i * 256 + threadIdx.x;           // 0..511 = ks*64 + ln*4 + lg
    int ks = j >> 6, ln = (j >> 2) & 15, lg = j & 3;
    const float* src = W + (size_t)(og * 16 + ln) * 256 + ks * 32 + lg * 8;
    short8 vv;
    #pragma unroll
    for (int e = 0; e < 8; ++e) vv[e] = (short)f2bf(src[e]);
    ((short8*)Wf)[og * 512 + j] = vv;
  }
}

// ---------------------------------------------------------------------------
// kf/kb tables: kf[h][d] = sum_n Re(c0_n w_n^d), kb same with c1.
// ---------------------------------------------------------------------------
__global__ __launch_bounds__(256) void kprep_kernel(const float* __restrict__ P,
                                                    float* __restrict__ Kf,
                                                    float* __restrict__ Kb) {
  int i = blockIdx.x * 256 + threadIdx.x;   // h*256 + d
  int d = i & 255, h = i >> 8;
  float fd = (float)d;
  float sf = 0.f, sb = 0.f;
  #pragma unroll 4
  for (int n = 0; n < NHD; ++n) {
    int j = h * NHD + n;
    float m  = __expf(fd * P[8*HN + j]);
    float ph = fd * P[9*HN + j];
    float cs = cosf(ph), sn = sinf(ph);
    float re = m * cs, im = m * sn;
    sf += P[2*HN + j] * re - P[3*HN + j] * im;
    sb += P[4*HN + j] * re - P[5*HN + j] * im;
  }
  Kf[i] = sf;
  Kb[i] = sb;
}

// ---------------------------------------------------------------------------
// T' fragment-order: chunk idx (((h*16+tt)*8+ks)*16+ln)*4+lg holds
// T[t=tt*16+ln][s=ks*32+lg*8+e], e in [0,8).
// ---------------------------------------------------------------------------
__global__ __launch_bounds__(256) void tprep_kernel(const float* __restrict__ Kf,
                                                    const float* __restrict__ Kb,
                                                    const float* __restrict__ Dv,
                                                    unsigned short* __restrict__ T) {
  int h = blockIdx.x, tt = blockIdx.y;
  const float* kf = Kf + h * 256;
  const float* kb = Kb + h * 256;
  float dh = Dv[h];
  short8* out = (short8*)T;
  #pragma unroll
  for (int i = 0; i < 2; ++i) {
    int j = i * 256 + threadIdx.x;          // 0..511 = ks*64 + ln*4 + lg
    int ks = j >> 6, ln = (j >> 2) & 15, lg = j & 3;
    int t = tt * 16 + ln;
    short8 vv;
    #pragma unroll
    for (int e = 0; e < 8; ++e) {
      int s = ks * 32 + lg * 8 + e;
      int d = t - s;
      float v = (d > 0) ? kf[d] : ((d < 0) ? kb[-d - 1] : (kf[0] + dh));
      vv[e] = (short)f2bf(v);
    }
    out[(size_t)(h * 16 + tt) * 512 + j] = vv;
  }
}

// ---------------------------------------------------------------------------
// E' fragment-order: chunk (((h*16+tt)*4+ks)*16+ln)*4+lg holds E[t][k].
// ---------------------------------------------------------------------------
__global__ __launch_bounds__(256) void eprep_kernel(const float* __restrict__ P,
                                                    unsigned short* __restrict__ E) {
  int h = blockIdx.x, tt = blockIdx.y;
  int j = threadIdx.x;                       // 0..255 = ks*64 + ln*4 + lg
  int ks = j >> 6, ln = (j >> 2) & 15, lg = j & 3;
  int t = tt * 16 + ln;
  int k0 = ks * 32 + lg * 8;
  short8 vv;
  if (k0 < 64) {
    float d = (float)(t + 1);
    #pragma unroll
    for (int q = 0; q < 4; ++q) {
      int n = (k0 >> 1) + q;
      int idx = h * NHD + n;
      float m  = __expf(d * P[8*HN + idx]);
      float ph = d * P[9*HN + idx];
      float re = m * cosf(ph), im = m * sinf(ph);
      float cr = P[2*HN + idx], ci = P[3*HN + idx];
      float zr = cr * re - ci * im;
      float zi = cr * im + ci * re;
      vv[2*q]   = (short)f2bf(zr);
      vv[2*q+1] = (short)f2bf(-zi);
    }
  } else {
    float d = (float)(LC - 1 - t);
    #pragma unroll
    for (int q = 0; q < 4; ++q) {
      int n = ((k0 - 64) >> 1) + q;
      int idx = h * NHD + n;
      float m  = __expf(d * P[8*HN + idx]);
      float ph = d * P[9*HN + idx];
      float re = m * cosf(ph), im = m * sinf(ph);
      float cr = P[4*HN + idx], ci = P[5*HN + idx];
      float zr = cr * re - ci * im;
      float zi = cr * im + ci * re;
      vv[2*q]   = (short)f2bf(zr);
      vv[2*q+1] = (short)f2bf(-zi);
    }
  }
  ((short8*)E)[(size_t)(h * 16 + tt) * 256 + j] = vv;
}

// ---------------------------------------------------------------------------
// V' fragment-order: chunk (((h*8+mt)*8+ks)*16+ln)*4+lg.
// ---------------------------------------------------------------------------
__global__ __launch_bounds__(256) void vprep_kernel(const float* __restrict__ P,
                                                    unsigned short* __restrict__ V) {
  int h = blockIdx.x, mt = blockIdx.y;       // mt in [0,8)
  #pragma unroll
  for (int i = 0; i < 2; ++i) {
    int j = i * 256 + threadIdx.x;           // 0..511
    int ks = j >> 6, ln = (j >> 2) & 15, lg = j & 3;
    int row = mt * 16 + ln;
    int dir = row >> 6, nc = row & 63;
    int n = nc >> 1, comp = nc & 1;
    int idx = h * NHD + n;
    float arn = P[8*HN + idx], ain = P[9*HN + idx];
    short8 vv;
    #pragma unroll
    for (int e = 0; e < 8; ++e) {
      int s = ks * 32 + lg * 8 + e;
      float d = (float)(dir ? s : (LC - 1 - s));
      float m = __expf(d * arn);
      float ph = d * ain;
      float v = m * (comp ? sinf(ph) : cosf(ph));
      vv[e] = (short)f2bf(v);
    }
    ((short8*)V)[(size_t)(h * 8 + mt) * 512 + j] = vv;
  }
}

// ---------------------------------------------------------------------------
// x (L,B,H) f32 -> UF fragment-order bf16.
// ---------------------------------------------------------------------------
__global__ __launch_bounds__(256) void transpose_kernel(const float* __restrict__ x,
                                                        unsigned short* __restrict__ UF) {
  __shared__ unsigned short tile[32][264];
  int b  = blockIdx.x;
  int lb = blockIdx.y * 32;
  int tid = threadIdx.x;
  int g = lb >> 8, ks = (lb & 255) >> 5;
  int inst = b * 32 + g, it = inst >> 4, lnw = inst & 15;
  #pragma unroll
  for (int i = 0; i < 8; ++i) {
    int idx = i * 256 + tid;                 // 0..2047
    int row = idx >> 6, c4 = idx & 63;
    float4 v = *(const float4*)(x + (size_t)(lb + row) * BH + b * 256 + c4 * 4);
    ushort4 u4v;
    u4v.x = f2bf(v.x); u4v.y = f2bf(v.y); u4v.z = f2bf(v.z); u4v.w = f2bf(v.w);
    *(ushort4*)&tile[row][c4 * 4] = u4v;
  }
  __syncthreads();
  short8* out = (short8*)UF;
  #pragma unroll
  for (int i = 0; i < 4; ++i) {
    int j = i * 256 + tid;                   // 0..1023
    int h = j >> 2, lg = j & 3;
    short8 vv;
    #pragma unroll
    for (int e = 0; e < 8; ++e) vv[e] = (short)tile[lg * 8 + e][h];
    out[(size_t)(h * 32 + it) * 512 + ks * 64 + lnw * 4 + lg] = vv;
  }
}

// ---------------------------------------------------------------------------
// B-fragment loaders: contiguous 1KB wave-loads.
// ---------------------------------------------------------------------------
__device__ __forceinline__ void load_bu(const short8* __restrict__ U8, int h, int it,
                                        int ln, int lg, short8 (&Bf)[8]) {
  size_t ub = (size_t)(h * 32 + it) * 512 + ln * 4 + lg;
  #pragma unroll
  for (int ks = 0; ks < 8; ++ks) Bf[ks] = U8[ub + ks * 64];
}
__device__ __forceinline__ void load_bs(const short8* __restrict__ S8, int h, int it,
                                        int ln, int lg, short8 (&Sf)[4]) {
  size_t sb = (size_t)(h * 32 + it) * 256 + ln * 4 + lg;
  #pragma unroll
  for (int ks = 0; ks < 4; ++ks) Sf[ks] = S8[sb + ks * 64];
}

// ---------------------------------------------------------------------------
// Fused chunk-final states + cross-chunk scan. ONE block per h.
// Phase 1 (8 waves, wave w = k-tile mt=w): Sfin -> LDS (128 KB, XOR-swizzled
// word = inst*64 + (kw ^ ((inst&7)<<2))); 4-deep U prefetch.
// Phase 2 (thread = (b,n)): sequential scan over g, writes Sc (global,
// fragment order, identical addresses/values to the old scanB kernel).
// ---------------------------------------------------------------------------
__global__ __launch_bounds__(512, 1) void sfin_scan(const unsigned short* __restrict__ V,
                                                    const unsigned short* __restrict__ UF,
                                                    const float* __restrict__ P,
                                                    unsigned short* __restrict__ Sc) {
  __shared__ unsigned int SL[32768];   // 128 KB
  int tid = threadIdx.x, w = tid >> 6, lane = tid & 63;
  int ln = lane & 15, lg = lane >> 4;
  int h = blockIdx.x;
  const short8* U8 = (const short8*)UF;
  const short8* V8 = (const short8*)V;

  short8 Vf[8];
  size_t vb = (size_t)(h * 8 + w) * 512 + ln * 4 + lg;
  #pragma unroll
  for (int ks = 0; ks < 8; ++ks) Vf[ks] = V8[vb + ks * 64];

  short8 B0[8], B1[8], B2[8], B3[8];
  load_bu(U8, h, 0, ln, lg, B0);
  load_bu(U8, h, 1, ln, lg, B1);
  load_bu(U8, h, 2, ln, lg, B2);

#define SFIN_STEP(BF, IT) { \
    floatx4 acc = (floatx4){0.f, 0.f, 0.f, 0.f}; \
    _Pragma("unroll") \
    for (int ks = 0; ks < 8; ++ks) \
      acc = __builtin_amdgcn_mfma_f32_16x16x32_bf16(Vf[ks], BF[ks], acc, 0, 0, 0); \
    int inst = (IT) * 16 + ln; \
    int kw = w * 8 + lg * 2; \
    int word = inst * 64 + (kw ^ ((inst & 7) << 2)); \
    uint2 pv; pv.x = packbf2(acc[0], acc[1]); pv.y = packbf2(acc[2], acc[3]); \
    *(uint2*)&SL[word] = pv; }

  for (int base = 0; base < 32; base += 4) {
    if (base + 3 < 32) load_bu(U8, h, base + 3, ln, lg, B3);
    SFIN_STEP(B0, base)
    if (base + 4 < 32) load_bu(U8, h, base + 4, ln, lg, B0);
    SFIN_STEP(B1, base + 1)
    if (base + 5 < 32) load_bu(U8, h, base + 5, ln, lg, B1);
    SFIN_STEP(B2, base + 2)
    if (base + 6 < 32) load_bu(U8, h, base + 6, ln, lg, B2);
    SFIN_STEP(B3, base + 3)
  }
#undef SFIN_STEP
  __syncthreads();

  // Phase 2: cross-chunk scan. thread = b*32 + n.
  int b = tid >> 5, n = tid & 31;
  float wlr = P[6*HN + h*NHD + n], wli = P[7*HN + h*NHD + n];
  unsigned* sc = (unsigned*)Sc;
  {
    int k = 2 * n;
    int ks = k >> 5, lgq = (k & 31) >> 3, eh = (k & 7) >> 1;
    float ar = 0.f, ai = 0.f;
    for (int g = 0; g < NG; ++g) {
      int inst = b * NG + g;
      int it = inst >> 4, lnn = inst & 15;
      size_t chunk = (size_t)(h * 32 + it) * 256 + ks * 64 + lnn * 4 + lgq;
      sc[chunk * 4 + eh] = packbf2(ar, ai);
      unsigned pv = SL[inst * 64 + (n ^ ((inst & 7) << 2))];
      float lr = bf2f((unsigned short)(pv & 0xFFFF));
      float li = bf2f((unsigned short)(pv >> 16));
      float nr = lr + wlr * ar - wli * ai;
      float ni = li + wlr * ai + wli * ar;
      ar = nr; ai = ni;
    }
  }
  {
    int k = 64 + 2 * n;
    int ks = k >> 5, lgq = (k & 31) >> 3, eh = (k & 7) >> 1;
    float ar = 0.f, ai = 0.f;
    for (int g = NG - 1; g >= 0; --g) {
      int inst = b * NG + g;
      int it = inst >> 4, lnn = inst & 15;
      size_t chunk = (size_t)(h * 32 + it) * 256 + ks * 64 + lnn * 4 + lgq;
      sc[chunk * 4 + eh] = packbf2(ar, ai);
      unsigned pv = SL[inst * 64 + ((32 + n) ^ ((inst & 7) << 2))];
      float lr = bf2f((unsigned short)(pv & 0xFFFF));
      float li = bf2f((unsigned short)(pv >> 16));
      float nr = lr + wlr * ar - wli * ai;
      float ni = li + wlr * ai + wli * ar;
      ar = nr; ai = ni;
    }
  }
}

// ---------------------------------------------------------------------------
// Fused local Toeplitz conv + correction + gelu: y = gelu(T'_h.u + E'_h.Sc).
// ONE block per h; T'/E' register-resident; 3-deep rotating B/S prefetch.
// ---------------------------------------------------------------------------
__device__ __forceinline__ void comp_y(const short8 (&Tf)[2][8], const short8 (&Ef)[2][4],
                                       const short8 (&Bf)[8], const short8 (&Sf)[4],
                                       int h, int it, int w, int ln, int lg,
                                       unsigned short* __restrict__ Y2) {
  int inst = it * 16 + ln, bb = inst >> 5, g = inst & 31;
  unsigned short* yrow = Y2 + (size_t)(bb * 256 + h) * LL + g * 256;
  #pragma unroll
  for (int t2 = 0; t2 < 2; ++t2) {
    int tt = w * 2 + t2;
    floatx4 acc = (floatx4){0.f, 0.f, 0.f, 0.f};
    #pragma unroll
    for (int ks = 0; ks < 8; ++ks)
      acc = __builtin_amdgcn_mfma_f32_16x16x32_bf16(Tf[t2][ks], Bf[ks], acc, 0, 0, 0);
    #pragma unroll
    for (int ks = 0; ks < 4; ++ks)
      acc = __builtin_amdgcn_mfma_f32_16x16x32_bf16(Ef[t2][ks], Sf[ks], acc, 0, 0, 0);
    float y0 = gelu_t(acc[0]), y1 = gelu_t(acc[1]);
    float y2v = gelu_t(acc[2]), y3 = gelu_t(acc[3]);
    uint2 vv; vv.x = packbf2(y0, y1); vv.y = packbf2(y2v, y3);
    *(uint2*)(yrow + tt * 16 + lg * 4) = vv;
  }
}

__global__ __launch_bounds__(512, 2) void yloc_corr(const unsigned short* __restrict__ T,
                                                    const unsigned short* __restrict__ E,
                                                    const unsigned short* __restrict__ Sc,
                                                    const unsigned short* __restrict__ UF,
                                                    unsigned short* __restrict__ Y2) {
  int tid = threadIdx.x, w = tid >> 6, lane = tid & 63;
  int ln = lane & 15, lg = lane >> 4;
  int h = blockIdx.x;
  const short8* T8 = (const short8*)T;
  const short8* E8 = (const short8*)E;
  const short8* S8 = (const short8*)Sc;
  const short8* U8 = (const short8*)UF;

  short8 Tf[2][8], Ef[2][4];
  #pragma unroll
  for (int t2 = 0; t2 < 2; ++t2) {
    int tt = w * 2 + t2;
    size_t tb = (size_t)(h * 16 + tt) * 512 + ln * 4 + lg;
    #pragma unroll
    for (int ks = 0; ks < 8; ++ks) Tf[t2][ks] = T8[tb + ks * 64];
    size_t eb = (size_t)(h * 16 + tt) * 256 + ln * 4 + lg;
    #pragma unroll
    for (int ks = 0; ks < 4; ++ks) Ef[t2][ks] = E8[eb + ks * 64];
  }

  short8 B0[8], B1[8], B2[8];
  short8 S0[4], S1[4], S2[4];
  load_bu(U8, h, 0, ln, lg, B0); load_bs(S8, h, 0, ln, lg, S0);
  load_bu(U8, h, 1, ln, lg, B1); load_bs(S8, h, 1, ln, lg, S1);

  for (int base = 0; base < 30; base += 3) {
    load_bu(U8, h, base + 2, ln, lg, B2); load_bs(S8, h, base + 2, ln, lg, S2);
    comp_y(Tf, Ef, B0, S0, h, base, w, ln, lg, Y2);
    load_bu(U8, h, base + 3, ln, lg, B0); load_bs(S8, h, base + 3, ln, lg, S0);
    comp_y(Tf, Ef, B1, S1, h, base + 1, w, ln, lg, Y2);
    if (base + 4 < 32) { load_bu(U8, h, base + 4, ln, lg, B1); load_bs(S8, h, base + 4, ln, lg, S1); }
    comp_y(Tf, Ef, B2, S2, h, base + 2, w, ln, lg, Y2);
  }
  comp_y(Tf, Ef, B0, S0, h, 30, w, ln, lg, Y2);
  comp_y(Tf, Ef, B1, S1, h, 31, w, ln, lg, Y2);
}

// ---------------------------------------------------------------------------
// MFMA GEMM + GLU, fused transpose staging; BN=64, 512 thr, 3 blocks/CU.
// (byte-identical to R13)
// ---------------------------------------------------------------------------
#define RAW_W 258   // u16 per raw row (+2 pad)
__global__ __launch_bounds__(512, 4) void gemm_mfma(
    const unsigned short* __restrict__ Wf,
    const unsigned short* __restrict__ Y2,
    const float* __restrict__ bvec, float* __restrict__ out) {
  __shared__ __align__(16) unsigned short ldsB[16384];      // 32 KB
  __shared__ unsigned short raw[32 * RAW_W];                // 16.1 KB
  int tid  = threadIdx.x;
  int w    = tid >> 6;
  int lane = tid & 63;
  int ln = lane & 15, lg = lane >> 4;
  int b  = blockIdx.x >> 7;
  int l0 = (blockIdx.x & 127) << 6;

  const short8* W8 = (const short8*)Wf;

  #pragma unroll
  for (int sl = 0; sl < 2; ++sl) {
    {
      int h = tid >> 1, lc = tid & 1;
      const unsigned short* src = Y2 + (((size_t)(b * 256 + h)) << 13) + l0 + sl * 32 + lc * 16;
      short8 v0 = ((const short8*)src)[0];
      short8 v1 = ((const short8*)src)[1];
      #pragma unroll
      for (int e = 0; e < 8; ++e) raw[(lc * 16 + e) * RAW_W + h] = (unsigned short)v0[e];
      #pragma unroll
      for (int e = 0; e < 8; ++e) raw[(lc * 16 + 8 + e) * RAW_W + h] = (unsigned short)v1[e];
    }
    __syncthreads();
    {
      int c = tid & 31, lq = tid >> 5;
      #pragma unroll
      for (int s2 = 0; s2 < 2; ++s2) {
        int lpp = lq + s2 * 16;
        int l = sl * 32 + lpp;
        short8 vv;
        #pragma unroll
        for (int e = 0; e < 8; ++e) vv[e] = (short)raw[lpp * RAW_W + c * 8 + e];
        ((short8*)ldsB)[l * 32 + (c ^ (l & 7))] = vv;
      }
    }
    __syncthreads();
  }

  floatx4 acc[4][4];
  #pragma unroll
  for (int m = 0; m < 4; ++m)
    #pragma unroll
    for (int n = 0; n < 4; ++n) acc[m][n] = (floatx4){0.f, 0.f, 0.f, 0.f};

  const short8* L8 = (const short8*)ldsB;
  #pragma unroll
  for (int ks = 0; ks < 8; ++ks) {
    short8 Bf[4];
    #pragma unroll
    for (int nf = 0; nf < 4; ++nf) {
      int row = nf * 16 + ln;
      Bf[nf] = L8[row * 32 + ((ks * 4 + lg) ^ (row & 7))];
    }
    #pragma unroll
    for (int mm = 0; mm < 4; ++mm) {
      int og = w * 2 + (mm & 1) + (mm >> 1) * 16;
      short8 Af = W8[(size_t)(og * 8 + ks) * 64 + ln * 4 + lg];
      #pragma unroll
      for (int nf = 0; nf < 4; ++nf)
        acc[mm][nf] = __builtin_amdgcn_mfma_f32_16x16x32_bf16(Af, Bf[nf], acc[mm][nf], 0, 0, 0);
    }
  }

  #pragma unroll
  for (int mm = 0; mm < 2; ++mm) {
    int obase = w * 32 + mm * 16 + lg * 4;
    #pragma unroll
    for (int r = 0; r < 4; ++r) {
      int o = obase + r;
      float b0 = bvec[o];
      float b1 = bvec[HH + o];
      float* op = out + ((size_t)(b * HH + o)) * LL + l0 + ln;
      #pragma unroll
      for (int nf = 0; nf < 4; ++nf) {
        float z1 = acc[mm][nf][r] + b0;
        float z2 = acc[mm + 2][nf][r] + b1;
        op[nf * 16] = z1 / (1.f + __expf(-z2));
      }
    }
  }
}

// ---------------------------------------------------------------------------
extern "C" void kernel_launch(void* const* d_in, const int* in_sizes, int n_in,
                              void* d_out, int out_size, void* d_ws, size_t ws_size,
                              hipStream_t stream) {
  const float* x      = (const float*)d_in[0];
  const float* log_dt = (const float*)d_in[1];
  const float* A_real = (const float*)d_in[2];
  const float* A_imag = (const float*)d_in[3];
  const float* C_real = (const float*)d_in[4];
  const float* C_imag = (const float*)d_in[5];
  const float* Dv     = (const float*)d_in[6];
  const float* W      = (const float*)d_in[7];
  const float* bvec   = (const float*)d_in[8];
  float* out = (float*)d_out;

  // ws: all regions dedicated (no aliasing). d_out not used as scratch.
  char* ws = (char*)d_ws;
  float*          P  = (float*)ws;                          // 320 KB
  unsigned short* Wf = (unsigned short*)(ws + 524288);      // 256 KB
  float*          Kf = (float*)(ws + 786432);               // 256 KB
  float*          Kb = (float*)(ws + 1048576);              // 256 KB
  size_t OFF_UF = (size_t)2 << 20;                          // [2, 66) MiB
  size_t OFF_T  = OFF_UF + ((size_t)256 * 32 * 512 * 16);   // [66, 98) MiB
  size_t OFF_E  = OFF_T + ((size_t)256 * 16 * 512 * 16);    // [98, 114) MiB
  size_t OFF_V  = OFF_E + ((size_t)256 * 16 * 256 * 16);    // [114, 130) MiB
  size_t OFF_SC = OFF_V + ((size_t)256 * 8 * 512 * 16);     // [130, 162) MiB
  size_t OFF_Y2 = OFF_SC + ((size_t)256 * 32 * 256 * 16);   // [162, 226) MiB
  unsigned short* UF = (unsigned short*)(ws + OFF_UF);
  unsigned short* T  = (unsigned short*)(ws + OFF_T);
  unsigned short* E  = (unsigned short*)(ws + OFF_E);
  unsigned short* V  = (unsigned short*)(ws + OFF_V);
  unsigned short* Sc = (unsigned short*)(ws + OFF_SC);
  unsigned short* Y2 = (unsigned short*)(ws + OFF_Y2);

  precomp_kernel<<<HN / 256, 256, 0, stream>>>(log_dt, A_real, A_imag, C_real, C_imag, P);
  wt_frag_kernel<<<32, 256, 0, stream>>>(W, Wf);
  kprep_kernel<<<HH * 256 / 256, 256, 0, stream>>>(P, Kf, Kb);
  tprep_kernel<<<dim3(HH, 16), 256, 0, stream>>>(Kf, Kb, Dv, T);
  eprep_kernel<<<dim3(HH, 16), 256, 0, stream>>>(P, E);
  vprep_kernel<<<dim3(HH, 8), 256, 0, stream>>>(P, V);
  transpose_kernel<<<dim3(BB, LL / 32), 256, 0, stream>>>(x, UF);
  sfin_scan<<<HH, 512, 0, stream>>>(V, UF, P, Sc);
  yloc_corr<<<HH, 512, 0, stream>>>(T, E, Sc, UF, Y2);
  gemm_mfma<<<BB * (LL / 64), 512, 0, stream>>>(Wf, Y2, bvec, out);
}